// Round 13
// baseline (74.994 us; speedup 1.0000x reference)
//
#include <hip/hip_runtime.h>

#define DM 2048
#define NG 64
#define TPB 256         // tokens per block
#define NSL 8           // k-slices
#define KSL 256         // k per slice
#define WK 32           // k per window
#define NWIN 8          // windows per slice
#define EPSV 1e-8f

typedef __attribute__((ext_vector_type(4))) float f32x4;
typedef __attribute__((ext_vector_type(16))) float f32x16;
typedef __attribute__((ext_vector_type(4))) int i32x4;
typedef __attribute__((ext_vector_type(4))) unsigned int u32x4;
typedef __attribute__((ext_vector_type(8))) short bf16x8;

__device__ __forceinline__ void stage16(const float* gsrc, float* ldst) {
  __builtin_amdgcn_global_load_lds(
      (const __attribute__((address_space(1))) unsigned int*)gsrc,
      (__attribute__((address_space(3))) unsigned int*)ldst, 16, 0, 0);
}

// split 8 fp32 into hi (truncate) / lo (rne residual) bf16.
__device__ __forceinline__ void split8(f32x4 x0, f32x4 x1, bf16x8& ah, bf16x8& al) {
  u32x4 u0 = __builtin_bit_cast(u32x4, x0);
  u32x4 u1 = __builtin_bit_cast(u32x4, x1);
  i32x4 hi;
  hi.x = (int)((u0.x >> 16) | (u0.y & 0xffff0000u));
  hi.y = (int)((u0.z >> 16) | (u0.w & 0xffff0000u));
  hi.z = (int)((u1.x >> 16) | (u1.y & 0xffff0000u));
  hi.w = (int)((u1.z >> 16) | (u1.w & 0xffff0000u));
  u32x4 m0 = u0 & 0xffff0000u;
  u32x4 m1 = u1 & 0xffff0000u;
  f32x4 r0 = x0 - __builtin_bit_cast(f32x4, m0);
  f32x4 r1 = x1 - __builtin_bit_cast(f32x4, m1);
  int lo0, lo1, lo2, lo3;
  asm("v_cvt_pk_bf16_f32 %0, %1, %2" : "=v"(lo0) : "v"(r0.x), "v"(r0.y));
  asm("v_cvt_pk_bf16_f32 %0, %1, %2" : "=v"(lo1) : "v"(r0.z), "v"(r0.w));
  asm("v_cvt_pk_bf16_f32 %0, %1, %2" : "=v"(lo2) : "v"(r1.x), "v"(r1.y));
  asm("v_cvt_pk_bf16_f32 %0, %1, %2" : "=v"(lo3) : "v"(r1.z), "v"(r1.w));
  i32x4 lo; lo.x = lo0; lo.y = lo1; lo.z = lo2; lo.w = lo3;
  ah = __builtin_bit_cast(bf16x8, hi);
  al = __builtin_bit_cast(bf16x8, lo);
}

// ---------------- Kernel 0: W split + counter reset (R7 layout) ----------------
// Fragment (S,h,n) at unit tg = S*128 + h*64 + n (8 shorts each); k = S*16+h*8+j.
__global__ __launch_bounds__(256) void moe_prep(
    const float* __restrict__ W, unsigned short* __restrict__ whp,
    unsigned short* __restrict__ wlp, int* __restrict__ counter)
{
  int tg = blockIdx.x * 256 + threadIdx.x;   // 128*2*64 fragments
  if (tg == 0) *counter = 0;
  int S = tg >> 7, h = (tg >> 6) & 1, n = tg & 63;
  const float* src = &W[(size_t)n * DM + S * 16 + h * 8];
  f32x4 w0 = *(const f32x4*)&src[0];
  f32x4 w1 = *(const f32x4*)&src[4];
  bf16x8 ah, al;
  split8(w0, w1, ah, al);
  *(bf16x8*)&whp[(size_t)tg * 8] = ah;
  *(bf16x8*)&wlp[(size_t)tg * 8] = al;
}

// ---------------- Kernel 1: low-traffic split-K=8 MFMA GEMM ----------------
// Block = 256 tok x 64 grp x 256 k. 512 thr / 8 waves (4 tok-quadrant x 2 grp-half),
// wave = 64 tok x 32 grp. x AND B staged to LDS per 32-k window (B once per block
// instead of per wave: chip B traffic 256 MB -> 32 MB). COMPUTE is pure-LDS.
__global__ __launch_bounds__(512, 4) void moe_gemm(
    const float* __restrict__ x, const unsigned short* __restrict__ whp,
    const unsigned short* __restrict__ wlp, float* __restrict__ out,
    float* __restrict__ pws, int mtok)
{
  __shared__ float xbuf[2][TPB * WK];   // 2 x 32 KB
  __shared__ bf16x8 bbuf[2][512];       // 2 x 8 KB: units 0-255 hi, 256-511 lo

  const int tid  = threadIdx.x;
  const int lane = tid & 63;
  const int ln   = lane & 31;
  const int h    = lane >> 5;
  const int wid  = tid >> 6;          // 0..7
  const int tq   = wid & 3;           // token quadrant (64 tok)
  const int gh   = wid >> 2;          // group half (32 grp)

  const int bid  = blockIdx.x;
  const int sl   = bid & 7;
  const int tok0 = (bid >> 3) * TPB;
  const int k0   = sl * KSL;

  auto stage_x = [&](int win, int b) {
    const float* xs = x + (size_t)tok0 * DM + k0 + win * WK;
    float* ld = &xbuf[b][0];
#pragma unroll
    for (int i = 0; i < 4; ++i) {
      int idx = i * 512 + tid;        // 16B slot; r=row, q=quad
      int r = idx >> 3, q = idx & 7;
      int sq = q ^ (r & 7);           // pre-swizzled source, linear dest
      stage16(xs + (size_t)r * DM + (sq << 2), ld + (idx << 2));
    }
  };
  auto stage_b = [&](int win, int b) {
    size_t boff = ((size_t)(k0 >> 4) + win * 2) * 2048;   // bytes into table
    const char* src = (tid < 256) ? ((const char*)whp + boff + tid * 16)
                                  : ((const char*)wlp + boff + (tid - 256) * 16);
    stage16((const float*)src, (float*)&bbuf[b][tid]);    // dest uniform+lane*16
  };

  f32x16 acc0 = {0.f,0.f,0.f,0.f,0.f,0.f,0.f,0.f,0.f,0.f,0.f,0.f,0.f,0.f,0.f,0.f};
  f32x16 acc1 = acc0;

#define COMPUTE(CC) do {                                                     \
    const float* xb_ = &xbuf[(CC) & 1][0];                                   \
    const bf16x8* bb_ = &bbuf[(CC) & 1][0];                                  \
    _Pragma("unroll")                                                        \
    for (int S = 0; S < 2; ++S) {                                            \
      int bu = (S * 2 + h) * 64 + gh * 32 + ln;                              \
      bf16x8 Bh = bb_[bu];                                                   \
      bf16x8 Bl = bb_[256 + bu];                                             \
      {                                                                      \
        int row = tq * 64 + ln;                                              \
        int qa = S * 4 + h * 2;                                              \
        const float* xr = xb_ + row * WK;                                    \
        f32x4 x0 = *(const f32x4*)(xr + ((qa ^ (row & 7)) << 2));            \
        f32x4 x1 = *(const f32x4*)(xr + (((qa + 1) ^ (row & 7)) << 2));      \
        bf16x8 ah, al;                                                       \
        split8(x0, x1, ah, al);                                              \
        acc0 = __builtin_amdgcn_mfma_f32_32x32x16_bf16(ah, Bh, acc0, 0, 0, 0); \
        acc0 = __builtin_amdgcn_mfma_f32_32x32x16_bf16(al, Bh, acc0, 0, 0, 0); \
        acc0 = __builtin_amdgcn_mfma_f32_32x32x16_bf16(ah, Bl, acc0, 0, 0, 0); \
      }                                                                      \
      {                                                                      \
        int row = tq * 64 + 32 + ln;                                         \
        int qa = S * 4 + h * 2;                                              \
        const float* xr = xb_ + row * WK;                                    \
        f32x4 x0 = *(const f32x4*)(xr + ((qa ^ (row & 7)) << 2));            \
        f32x4 x1 = *(const f32x4*)(xr + (((qa + 1) ^ (row & 7)) << 2));      \
        bf16x8 ah, al;                                                       \
        split8(x0, x1, ah, al);                                              \
        acc1 = __builtin_amdgcn_mfma_f32_32x32x16_bf16(ah, Bh, acc1, 0, 0, 0); \
        acc1 = __builtin_amdgcn_mfma_f32_32x32x16_bf16(al, Bh, acc1, 0, 0, 0); \
        acc1 = __builtin_amdgcn_mfma_f32_32x32x16_bf16(ah, Bl, acc1, 0, 0, 0); \
      }                                                                      \
    }                                                                        \
  } while (0)

  stage_x(0, 0);
  stage_b(0, 0);
  __syncthreads();

#pragma unroll 1
  for (int c = 0; c < NWIN; ++c) {
    if (c < NWIN - 1) {
      stage_x(c + 1, (c + 1) & 1);
      stage_b(c + 1, (c + 1) & 1);
    }
    COMPUTE(c);                       // pure-LDS; stages stay in flight
    __syncthreads();                  // drains stage(c+1); co-resident blocks overlap
  }
#undef COMPUTE

  // partial logits (C/D map: n = gh*32+ln, m = tq*64 + tt*32 + (r&3)+8*(r>>2)+4*h)
  float* ps = (sl < 3) ? (out + (size_t)sl * mtok * NG)
                       : (pws + (size_t)(sl - 3) * mtok * NG);
#pragma unroll
  for (int r = 0; r < 16; ++r) {
    int mrow = (r & 3) + 8 * (r >> 2) + 4 * h;
    ps[(size_t)(tok0 + tq * 64 + mrow) * NG + gh * 32 + ln] = acc0[r];
    ps[(size_t)(tok0 + tq * 64 + 32 + mrow) * NG + gh * 32 + ln] = acc1[r];
  }
}

// ---------------- Kernel 2: reduce 8 slices + softmax + top-8 + flag + write ----------------
__global__ __launch_bounds__(256) void moe_finish(
    float* __restrict__ out, const float* __restrict__ pws,
    int* __restrict__ counter, int* __restrict__ flaglist, int mtok)
{
  const int tid = threadIdx.x;
  const int t   = blockIdx.x * 32 + (tid >> 3);
  const int l8  = tid & 7;
  const size_t MN = (size_t)mtok * NG;
  const size_t base = (size_t)t * NG + (l8 << 3);

  f32x4 a0 = {0.f, 0.f, 0.f, 0.f}, a1 = {0.f, 0.f, 0.f, 0.f};
#pragma unroll
  for (int s = 0; s < NSL; ++s) {
    const float* p = (s < 3) ? (out + (size_t)s * MN) : (pws + (size_t)(s - 3) * MN);
    a0 += *(const f32x4*)&p[base];
    a1 += *(const f32x4*)&p[base + 4];
  }

  float l[8];
#pragma unroll
  for (int j = 0; j < 4; ++j) { l[j] = a0[j]; l[j + 4] = a1[j]; }

  float m = l[0];
#pragma unroll
  for (int j = 1; j < 8; ++j) m = fmaxf(m, l[j]);
#pragma unroll
  for (int msk = 1; msk < 8; msk <<= 1) m = fmaxf(m, __shfl_xor(m, msk));

  float e[8];
  float sum = 0.f;
#pragma unroll
  for (int j = 0; j < 8; ++j) { e[j] = __expf(l[j] - m); sum += e[j]; }
#pragma unroll
  for (int msk = 1; msk < 8; msk <<= 1) sum += __shfl_xor(sum, msk);

  unsigned taken = 0;
  float esel = 0.f, e8 = 0.f, e9 = 0.f;
#pragma unroll 1
  for (int p = 0; p < 9; ++p) {
    float bv = -1.f;
    int bi = 127;
#pragma unroll
    for (int j = 0; j < 8; ++j) {
      bool avail = !((taken >> j) & 1u);
      float vv = e[j];
      int g = (l8 << 3) + j;
      bool better = avail && (vv > bv || (vv == bv && g < bi));
      bv = better ? vv : bv;
      bi = better ? g : bi;
    }
#pragma unroll
    for (int msk = 1; msk < 8; msk <<= 1) {
      float ov = __shfl_xor(bv, msk);
      int oi = __shfl_xor(bi, msk);
      bool better = (ov > bv) || (ov == bv && oi < bi);
      bv = better ? ov : bv;
      bi = better ? oi : bi;
    }
    if (p < 8) {
      esel += bv;
      if ((bi >> 3) == l8) taken |= 1u << (bi & 7);
      if (p == 7) e8 = bv;
    } else {
      e9 = bv;
    }
  }

  // flag near-ties for exact recompute: l8-l9 < 1e-3  <=>  e9 > e8*exp(-1e-3)
  if (l8 == 0 && e9 > e8 * 0.999f) {
    int ix = atomicAdd(counter, 1);
    flaglist[ix] = t;
  }

  const float inv = 1.f / sum;
  const float rsc = 1.f / (esel + EPSV * sum);

  f32x4 r0, r1, m0, m1, s0, s1;
#pragma unroll
  for (int j = 0; j < 4; ++j) {
    float bitL = ((taken >> j) & 1u) ? 1.f : 0.f;
    float bitH = ((taken >> (j + 4)) & 1u) ? 1.f : 0.f;
    s0[j] = e[j] * inv;      s1[j] = e[j + 4] * inv;
    m0[j] = bitL;            m1[j] = bitH;
    r0[j] = bitL * e[j] * rsc;
    r1[j] = bitH * e[j + 4] * rsc;
  }
  *(f32x4*)&out[base]              = r0;
  *(f32x4*)&out[base + 4]          = r1;
  *(f32x4*)&out[MN + base]         = m0;
  *(f32x4*)&out[MN + base + 4]     = m1;
  *(f32x4*)&out[2 * MN + base]     = s0;
  *(f32x4*)&out[2 * MN + base + 4] = s1;
}

// ---------------- Kernel 3: exact fp32 fixup, block-per-token ----------------
__global__ __launch_bounds__(256) void moe_fixup(
    const float* __restrict__ x, const float* __restrict__ W,
    float* __restrict__ out, const int* __restrict__ counter,
    const int* __restrict__ flaglist, int mtok)
{
  const int cnt = counter[0];
  const int g = threadIdx.x & 63;
  const int q = threadIdx.x >> 6;
  const size_t MN = (size_t)mtok * NG;
  __shared__ float part[4][64];

  for (int i = blockIdx.x; i < cnt; i += 256) {
    const int tok = flaglist[i];
    const float* xr = &x[(size_t)tok * DM + q * 512];
    const float* wr = &W[(size_t)g * DM + q * 512];
    f32x4 a = {0.f, 0.f, 0.f, 0.f};
#pragma unroll 8
    for (int k = 0; k < 512; k += 4)
      a += *(const f32x4*)&xr[k] * *(const f32x4*)&wr[k];
    part[q][g] = a.x + a.y + a.z + a.w;
    __syncthreads();

    if (q == 0) {
      float l = part[0][g] + part[1][g] + part[2][g] + part[3][g];

      float m = l;
#pragma unroll
      for (int msk = 1; msk < 64; msk <<= 1) m = fmaxf(m, __shfl_xor(m, msk));
      float e = __expf(l - m);
      float sum = e;
#pragma unroll
      for (int msk = 1; msk < 64; msk <<= 1) sum += __shfl_xor(sum, msk);

      bool sel = false;
#pragma unroll 1
      for (int p = 0; p < 8; ++p) {
        float bv = sel ? -3.4e38f : l;
        int bi = sel ? 1000 : g;
#pragma unroll
        for (int msk = 1; msk < 64; msk <<= 1) {
          float ov = __shfl_xor(bv, msk);
          int oi = __shfl_xor(bi, msk);
          bool better = (ov > bv) || (ov == bv && oi < bi);
          bv = better ? ov : bv;
          bi = better ? oi : bi;
        }
        if (bi == g) sel = true;
      }
      float esel = sel ? e : 0.f;
#pragma unroll
      for (int msk = 1; msk < 64; msk <<= 1) esel += __shfl_xor(esel, msk);

      const float inv = 1.f / sum;
      const float rsc = 1.f / (esel + EPSV * sum);
      const float bit = sel ? 1.f : 0.f;
      const size_t base = (size_t)tok * NG + g;
      out[base] = bit * e * rsc;
      out[MN + base] = bit;
      out[2 * MN + base] = e * inv;
    }
    __syncthreads();
  }
}

extern "C" void kernel_launch(void* const* d_in, const int* in_sizes, int n_in,
                              void* d_out, int out_size, void* d_ws, size_t ws_size,
                              hipStream_t stream) {
  const float* x = (const float*)d_in[0];
  const float* W = (const float*)d_in[1];
  float* out = (float*)d_out;
  const int mtok = in_sizes[0] / DM;          // 16384

  char* ws = (char*)d_ws;
  int* counter = (int*)ws;                               // @0
  int* flaglist = (int*)(ws + 4096);                     // 64 KB
  unsigned short* whp = (unsigned short*)(ws + 69632);   // 256 KB
  unsigned short* wlp = (unsigned short*)(ws + 331776);  // 256 KB
  float* pws = (float*)(ws + (1u << 20));                // 5 slices x 4 MB

  hipLaunchKernelGGL(moe_prep, dim3(64), dim3(256), 0, stream, W, whp, wlp, counter);
  hipLaunchKernelGGL(moe_gemm, dim3((mtok / TPB) * NSL), dim3(512), 0, stream,
                     x, whp, wlp, out, pws, mtok);
  hipLaunchKernelGGL(moe_finish, dim3(mtok / 32), dim3(256), 0, stream,
                     out, pws, counter, flaglist, mtok);
  hipLaunchKernelGGL(moe_fixup, dim3(256), dim3(256), 0, stream,
                     x, W, out, counter, flaglist, mtok);
}